// Round 2
// baseline (60.352 us; speedup 1.0000x reference)
//
#include <hip/hip_runtime.h>

// Problem constants (B,C,H,W = 8,1,88,128; TIMESTEPS=1000)
static constexpr int N       = 8 * 1 * 88 * 128;   // 90112 pixels
static constexpr int VEC     = 4;
static constexpr int NV      = N / VEC;            // 22528 float4 pairs
static constexpr int THREADS = 1024;               // 16 waves, one workgroup
static constexpr int PER_THR = NV / THREADS;       // 22, exact

// idx(x) = int(max(x*1000 - 1, 0)); _rn intrinsics forbid FMA contraction so
// quantization boundaries bit-match numpy's mul-then-sub (absmax was 0.0).
__device__ __forceinline__ int bucket(float x) {
    float v = __fsub_rn(__fmul_rn(x, 1000.0f), 1.0f);
    v = fmaxf(v, 0.0f);
    return (int)v;   // truncation toward zero == astype(int32) for v >= 0
}

// Single-workgroup fused kernel: count index mismatches M over all pixels,
// then loss = M*(1/(N*999) + 1/N).  One launch; no workspace needed.
__global__ __launch_bounds__(THREADS) void loss_kernel(
        const float4* __restrict__ r, const float4* __restrict__ t,
        float* __restrict__ out) {
    int c = 0;
    #pragma unroll
    for (int k = 0; k < PER_THR; ++k) {
        const int i = k * THREADS + threadIdx.x;   // coalesced, stride-1024
        const float4 rv = r[i];
        const float4 tv = t[i];
        c += (bucket(rv.x) != bucket(tv.x))
           + (bucket(rv.y) != bucket(tv.y))
           + (bucket(rv.z) != bucket(tv.z))
           + (bucket(rv.w) != bucket(tv.w));
    }
    // wave (64-lane) shuffle reduction
    #pragma unroll
    for (int off = 32; off > 0; off >>= 1)
        c += __shfl_down(c, off, 64);
    __shared__ int smem[THREADS / 64];   // 16 wave partials
    if ((threadIdx.x & 63) == 0) smem[threadIdx.x >> 6] = c;
    __syncthreads();
    if (threadIdx.x < 64) {
        int s = (threadIdx.x < THREADS / 64) ? smem[threadIdx.x] : 0;
        #pragma unroll
        for (int off = 8; off > 0; off >>= 1)
            s += __shfl_down(s, off, 64);
        if (threadIdx.x == 0) {
            // loss = M/(N*999) + M/N  (zero_loss + nonzero_loss), fp64 then round
            const double invN = 1.0 / (double)N;
            out[0] = (float)((double)s * (invN / 999.0 + invN));
        }
    }
}

extern "C" void kernel_launch(void* const* d_in, const int* in_sizes, int n_in,
                              void* d_out, int out_size, void* d_ws, size_t ws_size,
                              hipStream_t stream) {
    const float4* r = (const float4*)d_in[0];  // reconstructed_image, fp32
    const float4* t = (const float4*)d_in[1];  // target_image, fp32
    float* out = (float*)d_out;                // scalar fp32 loss

    loss_kernel<<<1, THREADS, 0, stream>>>(r, t, out);
}